// Round 4
// baseline (742.220 us; speedup 1.0000x reference)
//
#include <hip/hip_runtime.h>
#include <hip/hip_bf16.h>

// C2QAttention: softmax(sim[B,C,Q], axis=Q) @ enc[B,Q,D] -> out[B,C,D]
// B=32, C=4096, Q=512, D=512. fp32 in/out; bf16 MFMA with deferred
// normalization: out = (exp(sim) @ enc) * (1/rowsum).
// Structure: per block 256 C-rows as 8 pipelined subtiles of 32 rows:
//   loads(t+1) in flight  ||  GEMM(t) + stores(t)  ->  stage(t+1)  -> barrier

constexpr int Bn = 32;
constexpr int Cn = 4096;
constexpr int Qn = 512;
constexpr int Dn = 512;
constexpr int BM = 32;            // rows per subtile
constexpr int NSUB = 8;           // subtiles per block
constexpr int ROWS = BM * NSUB;   // 256 rows per block

typedef __attribute__((ext_vector_type(8))) short short8;
typedef __attribute__((ext_vector_type(4))) float floatx4;

__device__ __forceinline__ ushort f2bf(float f) {
  union { float f; unsigned u; } v; v.f = f;
  unsigned r = v.u + 0x7FFFu + ((v.u >> 16) & 1u);   // RNE
  return (ushort)(r >> 16);
}

// enc [B][Q][D] f32 -> Et [B][D][Q] bf16 (MFMA B-frags contiguous along Q)
__global__ __launch_bounds__(256) void transpose_conv(const float* __restrict__ E,
                                                      ushort* __restrict__ Et) {
  __shared__ float tile[32][33];
  int b = blockIdx.z, q0 = blockIdx.y * 32, d0 = blockIdx.x * 32;
  int x = threadIdx.x & 31, y = threadIdx.x >> 5;
  const float* src = E + ((size_t)b * Qn + q0) * Dn + d0;
#pragma unroll
  for (int k = 0; k < 4; ++k)
    tile[y + 8 * k][x] = src[(size_t)(y + 8 * k) * Dn + x];
  __syncthreads();
  ushort* dst = Et + ((size_t)b * Dn + d0) * Qn + q0;
#pragma unroll
  for (int k = 0; k < 4; ++k)
    dst[(size_t)(y + 8 * k) * Qn + x] = f2bf(tile[x][y + 8 * k]);
}

__global__ __launch_bounds__(512, 4) void c2q_fused(const float* __restrict__ sim,
                                                    const ushort* __restrict__ Et,
                                                    float* __restrict__ out) {
  __shared__ char Pbuf[2][BM * Qn * 2];   // 2 x 32 KB bf16, XOR-swizzled
  __shared__ float rsInv[2][BM];

  const int tid  = threadIdx.x;
  const int lane = tid & 63;
  const int wid  = tid >> 6;            // 0..7 -> 64 D-cols each
  const int l16  = lane & 15;
  const int lhi  = lane >> 4;           // 0..3

  // b-major grid: XCD = blockIdx.x % 8 = b % 8 -> 4 distinct b per XCD
  // -> Et working set 4 x 512 KB = 2 MB, fits 4 MB XCD L2.
  const int b  = blockIdx.x & 31;
  const int c0 = (blockIdx.x >> 5) * ROWS;

  // staging map: 16 threads per row, 32 floats each (8x float4, 256B/instr)
  const int srow = tid >> 4;            // 0..31
  const int skp  = tid & 15;            // 0..15
  const float* sload = sim + ((size_t)b * Cn + c0 + srow) * Qn + skp * 4;
  const int swz = (srow & 7) << 4;

  float4 v[8];

  // ---------------- prologue: stage subtile 0 ----------------
#pragma unroll
  for (int j = 0; j < 8; ++j) v[j] = *(const float4*)(sload + j * 64);
  {
    float rsum = 0.0f;
#pragma unroll
    for (int j = 0; j < 8; ++j) {
      float e0 = __expf(v[j].x), e1 = __expf(v[j].y);
      float e2 = __expf(v[j].z), e3 = __expf(v[j].w);
      rsum += (e0 + e1) + (e2 + e3);
      uint2 pk;
      pk.x = (uint)f2bf(e0) | ((uint)f2bf(e1) << 16);
      pk.y = (uint)f2bf(e2) | ((uint)f2bf(e3) << 16);
      *(uint2*)(Pbuf[0] + (((srow << 10) + (j << 7) + (skp << 3)) ^ swz)) = pk;
    }
    rsum += __shfl_xor(rsum, 1);
    rsum += __shfl_xor(rsum, 2);
    rsum += __shfl_xor(rsum, 4);
    rsum += __shfl_xor(rsum, 8);
    if (skp == 0) rsInv[0][srow] = 1.0f / rsum;
  }
  __syncthreads();

  // Et fragment base + 1-deep rotating prefetch (ks+1 wraps -> next subtile)
  const ushort* EtB = Et + ((size_t)b * Dn + wid * 64 + l16) * Qn + lhi * 8;
  short8 bb[4];
#pragma unroll
  for (int nr = 0; nr < 4; ++nr)
    bb[nr] = *(const short8*)(EtB + (size_t)nr * 16 * Qn);

  for (int t = 0; t < NSUB; ++t) {
    // ---- issue loads for subtile t+1 (consumed at end of iteration) ----
    if (t < NSUB - 1) {
      const float* nl = sload + (size_t)(t + 1) * BM * Qn;
#pragma unroll
      for (int j = 0; j < 8; ++j) v[j] = *(const float4*)(nl + j * 64);
    }
    __builtin_amdgcn_sched_barrier(0);  // keep load issue above the GEMM

    // ---- GEMM(t): 32 rows x 512 cols, K=512 ----
    floatx4 acc[2][4] = {};
    const char* pb = Pbuf[t & 1];
#pragma unroll
    for (int ks = 0; ks < 16; ++ks) {
      short8 nb[4];
#pragma unroll
      for (int nr = 0; nr < 4; ++nr)
        nb[nr] = *(const short8*)(EtB + (size_t)nr * 16 * Qn + ((ks + 1) & 15) * 32);
      short8 a[2];
#pragma unroll
      for (int mr = 0; mr < 2; ++mr) {
        int row = mr * 16 + l16;
        int off = ((row << 10) + (ks << 6) + (lhi << 4)) ^ ((row & 7) << 4);
        a[mr] = *(const short8*)(pb + off);
      }
      __builtin_amdgcn_s_setprio(1);
#pragma unroll
      for (int mr = 0; mr < 2; ++mr)
#pragma unroll
        for (int nr = 0; nr < 4; ++nr)
          acc[mr][nr] = __builtin_amdgcn_mfma_f32_16x16x32_bf16(a[mr], bb[nr],
                                                                acc[mr][nr], 0, 0, 0);
      __builtin_amdgcn_s_setprio(0);
#pragma unroll
      for (int nr = 0; nr < 4; ++nr) bb[nr] = nb[nr];
    }

    // ---- stores(t): writes flow mid-kernel, overlap the load wait ----
    float* outp = out + ((size_t)b * Cn + c0 + t * BM) * Dn;
#pragma unroll
    for (int mr = 0; mr < 2; ++mr) {
      float rs[4];
#pragma unroll
      for (int rr = 0; rr < 4; ++rr) rs[rr] = rsInv[t & 1][mr * 16 + lhi * 4 + rr];
#pragma unroll
      for (int nr = 0; nr < 4; ++nr) {
        int col = wid * 64 + nr * 16 + l16;
#pragma unroll
        for (int rr = 0; rr < 4; ++rr)
          outp[(size_t)(mr * 16 + lhi * 4 + rr) * Dn + col] = acc[mr][nr][rr] * rs[rr];
      }
    }

    // ---- stage(t+1): exp + pack + LDS write + rowsum ----
    if (t < NSUB - 1) {
      float rsum = 0.0f;
      char* wb = Pbuf[(t + 1) & 1];
#pragma unroll
      for (int j = 0; j < 8; ++j) {
        float e0 = __expf(v[j].x), e1 = __expf(v[j].y);
        float e2 = __expf(v[j].z), e3 = __expf(v[j].w);
        rsum += (e0 + e1) + (e2 + e3);
        uint2 pk;
        pk.x = (uint)f2bf(e0) | ((uint)f2bf(e1) << 16);
        pk.y = (uint)f2bf(e2) | ((uint)f2bf(e3) << 16);
        *(uint2*)(wb + (((srow << 10) + (j << 7) + (skp << 3)) ^ swz)) = pk;
      }
      rsum += __shfl_xor(rsum, 1);
      rsum += __shfl_xor(rsum, 2);
      rsum += __shfl_xor(rsum, 4);
      rsum += __shfl_xor(rsum, 8);
      if (skp == 0) rsInv[(t + 1) & 1][srow] = 1.0f / rsum;
    }
    __syncthreads();
  }
}

extern "C" void kernel_launch(void* const* d_in, const int* in_sizes, int n_in,
                              void* d_out, int out_size, void* d_ws, size_t ws_size,
                              hipStream_t stream) {
  const float* sim = (const float*)d_in[0];
  const float* enc = (const float*)d_in[1];
  float* outp = (float*)d_out;
  ushort* Et = (ushort*)d_ws;  // 32*512*512*2 = 16.8 MB

  transpose_conv<<<dim3(Dn / 32, Qn / 32, Bn), 256, 0, stream>>>(enc, Et);
  c2q_fused<<<dim3((Cn / ROWS) * Bn), 512, 0, stream>>>(sim, Et, outp);
}

// Round 5
// 334.381 us; speedup vs baseline: 2.2197x; 2.2197x over previous
//
#include <hip/hip_runtime.h>
#include <hip/hip_bf16.h>

// C2QAttention: softmax(sim[B,C,Q], axis=Q) @ enc[B,Q,D] -> out[B,C,D]
// B=32, C=4096, Q=512, D=512. fp32 in/out; bf16 MFMA, deferred normalization:
// out = (exp(sim) @ enc) * (1/rowsum).
//
// Structure: barrier-free, LDS-free fused kernel. Each wave independently owns
// a 32-row x 128-col output tile with full K=512:
//   - A-frags loaded DIRECTLY from sim (lane l16 = row, k = ks*32+lhi*8+j) in
//     2-ks batches (8 KB/wave in flight), exp'd + packed in registers.
//   - B-frags from fragment-major pre-formatted Etf: 1 KB coalesced dwordx4.
//   - rowsum per-lane, reduced with 2 shfl_xor at the end (wave sees all K).

constexpr int Bn = 32;
constexpr int Cn = 4096;
constexpr int Qn = 512;
constexpr int Dn = 512;

typedef __attribute__((ext_vector_type(8))) short short8;
typedef __attribute__((ext_vector_type(4))) float floatx4;

__device__ __forceinline__ ushort f2bf(float f) {
  union { float f; unsigned u; } v; v.f = f;
  unsigned r = v.u + 0x7FFFu + ((v.u >> 16) & 1u);   // RNE
  return (ushort)(r >> 16);
}

// enc[b][q][d] f32 -> Etf fragment-major: [b][dtile(32)][ks(16)][lane(64)]x16B
// chunk(b,dt,ks): lane=lhi*16+l16 holds bf16[j] = enc[b][ks*32+lhi*8+j][dt*16+l16]
__global__ __launch_bounds__(256) void enc_to_frag(const float* __restrict__ E,
                                                   ushort* __restrict__ Etf) {
  const int ks = blockIdx.x, b = blockIdx.y;
  const int t = threadIdx.x;
  const int lane = t & 63, grp = t >> 6;
  const int l16 = lane & 15, lhi = lane >> 4;
  const float* src = E + ((size_t)b * Qn + ks * 32 + lhi * 8) * Dn + l16;
#pragma unroll
  for (int dt8 = 0; dt8 < 8; ++dt8) {
    int dt = grp * 8 + dt8;
    float e[8];
#pragma unroll
    for (int j = 0; j < 8; ++j) e[j] = src[(size_t)j * Dn + dt * 16];
    uint4 pk;
    pk.x = (uint)f2bf(e[0]) | ((uint)f2bf(e[1]) << 16);
    pk.y = (uint)f2bf(e[2]) | ((uint)f2bf(e[3]) << 16);
    pk.z = (uint)f2bf(e[4]) | ((uint)f2bf(e[5]) << 16);
    pk.w = (uint)f2bf(e[6]) | ((uint)f2bf(e[7]) << 16);
    *(uint4*)((char*)Etf + (((size_t)(b * 32 + dt) * 16 + ks) * 64 + lane) * 16) = pk;
  }
}

__global__ __launch_bounds__(256, 2) void c2q_fused(const float* __restrict__ sim,
                                                    const ushort* __restrict__ Etf,
                                                    float* __restrict__ out) {
  const int t    = threadIdx.x;
  const int lane = t & 63;
  const int w    = t >> 6;             // 0..3 -> 128 D-cols each
  const int l16  = lane & 15;
  const int lhi  = lane >> 4;          // 0..3

  // b-pinned XCD grid: XCD = lin%8 serves b in {blo, 8+blo, 16+blo, 24+blo}
  // -> Et working set 4 x 512 KB = 2 MB per XCD L2; ct ascending per XCD.
  const int lin  = blockIdx.x;         // 4096 blocks
  const int blo  = lin & 7;
  const int rest = lin >> 3;
  const int bhi  = rest & 3;
  const int ct   = rest >> 2;          // 0..127
  const int b    = (bhi << 3) | blo;
  const int c0   = ct * 32;
  const int d0   = w * 128;

  // direct A-frag load bases (mr = 0,1): row = c0 + mr*16 + l16, k = lhi*8
  const float* s0 = sim + ((size_t)b * Cn + c0 + l16) * Qn + lhi * 8;
  const float* s1 = s0 + (size_t)16 * Qn;

  // B-frag base: chunk (b, dtile = w*8 + nr, ks), this lane's 16B
  const short8* EB = (const short8*)Etf + (((size_t)b * 32 + w * 8) * 16) * 64 + lane;

  floatx4 acc[2][8] = {};
  float r0 = 0.0f, r1 = 0.0f;

#pragma unroll 2
  for (int kb = 0; kb < 8; ++kb) {     // 8 batches x 2 ks
    float4 v[2][2][2];                  // [mr][kl][half] -- 8 KB/wave in flight
#pragma unroll
    for (int kl = 0; kl < 2; ++kl) {
      int ks = kb * 2 + kl;
      v[0][kl][0] = *(const float4*)(s0 + ks * 32);
      v[0][kl][1] = *(const float4*)(s0 + ks * 32 + 4);
      v[1][kl][0] = *(const float4*)(s1 + ks * 32);
      v[1][kl][1] = *(const float4*)(s1 + ks * 32 + 4);
    }
#pragma unroll
    for (int kl = 0; kl < 2; ++kl) {
      int ks = kb * 2 + kl;
      short8 bb[8];
#pragma unroll
      for (int nr = 0; nr < 8; ++nr) bb[nr] = EB[((size_t)nr * 16 + ks) * 64];
      short8 a[2];
#pragma unroll
      for (int mr = 0; mr < 2; ++mr) {
        float4 x = v[mr][kl][0], y = v[mr][kl][1];
        float e0 = __expf(x.x), e1 = __expf(x.y), e2 = __expf(x.z), e3 = __expf(x.w);
        float e4 = __expf(y.x), e5 = __expf(y.y), e6 = __expf(y.z), e7 = __expf(y.w);
        float s = ((e0 + e1) + (e2 + e3)) + ((e4 + e5) + (e6 + e7));
        if (mr == 0) r0 += s; else r1 += s;
        union { uint4 u; short8 s8; } pk;
        pk.u.x = (uint)f2bf(e0) | ((uint)f2bf(e1) << 16);
        pk.u.y = (uint)f2bf(e2) | ((uint)f2bf(e3) << 16);
        pk.u.z = (uint)f2bf(e4) | ((uint)f2bf(e5) << 16);
        pk.u.w = (uint)f2bf(e6) | ((uint)f2bf(e7) << 16);
        a[mr] = pk.s8;
      }
#pragma unroll
      for (int mr = 0; mr < 2; ++mr)
#pragma unroll
        for (int nr = 0; nr < 8; ++nr)
          acc[mr][nr] = __builtin_amdgcn_mfma_f32_16x16x32_bf16(
              mr == 0 ? a[0] : a[1], bb[nr], acc[mr][nr], 0, 0, 0);
    }
  }

  // rowsums: lane holds partial for row (mr*16 + l16) over its lhi k-slice;
  // lanes {l16, l16+16, l16+32, l16+48} sum to the full row sum.
  r0 += __shfl_xor(r0, 16); r0 += __shfl_xor(r0, 32);
  r1 += __shfl_xor(r1, 16); r1 += __shfl_xor(r1, 32);
  float inv0 = 1.0f / r0, inv1 = 1.0f / r1;

  // store: acc frag row-within-16 = lhi*4+rr, col = l16. Fetch the needed
  // row inverses from the lane that owns them (lane lhi*4+rr holds that row).
  float* outp = out + ((size_t)b * Cn + c0) * Dn + d0;
#pragma unroll
  for (int mr = 0; mr < 2; ++mr) {
    float rs[4];
#pragma unroll
    for (int rr = 0; rr < 4; ++rr)
      rs[rr] = __shfl(mr == 0 ? inv0 : inv1, lhi * 4 + rr);
#pragma unroll
    for (int nr = 0; nr < 8; ++nr) {
#pragma unroll
      for (int rr = 0; rr < 4; ++rr) {
        int row = mr * 16 + lhi * 4 + rr;
        outp[(size_t)row * Dn + nr * 16 + l16] = acc[mr][nr][rr] * rs[rr];
      }
    }
  }
}

extern "C" void kernel_launch(void* const* d_in, const int* in_sizes, int n_in,
                              void* d_out, int out_size, void* d_ws, size_t ws_size,
                              hipStream_t stream) {
  const float* sim = (const float*)d_in[0];
  const float* enc = (const float*)d_in[1];
  float* outp = (float*)d_out;
  ushort* Etf = (ushort*)d_ws;  // 32*32*16*64*16 B = 16.8 MB

  enc_to_frag<<<dim3(16, Bn), 256, 0, stream>>>(enc, Etf);
  c2q_fused<<<dim3(4096), 256, 0, stream>>>(sim, Etf, outp);
}